// Round 4
// baseline (90.050 us; speedup 1.0000x reference)
//
#include <hip/hip_runtime.h>
#include <hip/hip_bf16.h>

#define B_N   8192
#define DIN   512
#define DH    512
#define NACT  18
#define NTASK 16
#define BM    64
#define GBN   128
#define BK    64
#define NT_MAX 144
#define NSLOT  640

typedef __attribute__((ext_vector_type(8))) short  short8v;
typedef __attribute__((ext_vector_type(8))) unsigned short ushort8v;
typedef __attribute__((ext_vector_type(4))) float  float4v;
typedef __attribute__((ext_vector_type(2))) float  float2v;

typedef const __attribute__((address_space(1))) void* gas_ptr;
typedef __attribute__((address_space(3))) void* las_ptr;

__device__ __forceinline__ unsigned short f2bf(float f) {
  union { float f; unsigned int u; } c; c.f = f;
  unsigned int u = c.u;
  u += 0x7fffu + ((u >> 16) & 1u);   // RNE
  return (unsigned short)(u >> 16);
}

// ============================================================ hist + tiles + slot map
__global__ __launch_bounds__(1024) void k_hist(
    const int* __restrict__ task_id,
    int* __restrict__ tl_task, int* __restrict__ tl_row0, int* __restrict__ tl_cnt,
    int* __restrict__ ntile, int* __restrict__ slot_map, int* __restrict__ rowidx) {
  __shared__ int s_cnt[NTASK], s_cur[NTASK];
  __shared__ int s_tl[NT_MAX * 3 + 1];
  __shared__ int s_slot[NSLOT];
  int tid = threadIdx.x;
  if (tid < NTASK) s_cnt[tid] = 0;
  for (int i = tid; i < NSLOT; i += 1024) s_slot[i] = -1;
  __syncthreads();
  for (int i = tid; i < B_N; i += 1024) atomicAdd(&s_cnt[task_id[i]], 1);
  __syncthreads();
  if (tid == 0) {
    int acc = 0, nt = 0;
    for (int t = 0; t < NTASK; ++t) {
      int c = s_cnt[t]; s_cur[t] = acc;
      for (int r = 0; r < c; r += BM) {
        s_tl[nt * 3 + 0] = t;
        s_tl[nt * 3 + 1] = acc + r;
        s_tl[nt * 3 + 2] = (c - r < BM) ? (c - r) : BM;
        ++nt;
      }
      acc += c;
    }
    s_tl[NT_MAX * 3] = nt;
    // slot assignment: blocks of task t land on physical ids == t (mod 8) -> same XCD
    int qcnt[8];
#pragma unroll
    for (int r = 0; r < 8; ++r) qcnt[r] = 0;
    int ovf[96]; int novf = 0;
    for (int i = 0; i < nt; ++i) {
      int r = s_tl[i * 3] & 7;
      for (int c = 0; c < 4; ++c) {
        int q = qcnt[r]++;
        int v = (i << 2) | c;
        if (q < NSLOT / 8) s_slot[q * 8 + r] = v;
        else if (novf < 96) ovf[novf++] = v;
      }
    }
    int fs = 0;
    for (int o = 0; o < novf; ++o) {
      while (fs < NSLOT && s_slot[fs] >= 0) ++fs;
      if (fs < NSLOT) s_slot[fs] = ovf[o];
    }
  }
  __syncthreads();
  int nt = s_tl[NT_MAX * 3];
  if (tid == 0) *ntile = nt;
  for (int i = tid; i < nt; i += 1024) {
    tl_task[i] = s_tl[i * 3 + 0];
    tl_row0[i] = s_tl[i * 3 + 1];
    tl_cnt[i]  = s_tl[i * 3 + 2];
  }
  for (int i = tid; i < NSLOT; i += 1024) slot_map[i] = s_slot[i];
  for (int i = tid; i < B_N; i += 1024) {
    int t = task_id[i];
    rowidx[atomicAdd(&s_cur[t], 1)] = i;
  }
}

// ============================================================ prep: xs gather | W1T | W2T
__global__ __launch_bounds__(256) void k_prep(
    const float* __restrict__ x, const float* __restrict__ W1,
    const float* __restrict__ W2, const int* __restrict__ rowidx,
    short* __restrict__ xs, short* __restrict__ W1T, short* __restrict__ W2T) {
  __shared__ __align__(16) short ldsA[64][72];
  __shared__ float ldsB[64 * 19];
  int bx = blockIdx.x, tid = threadIdx.x;

  if (bx < 2048) {
    // xs gather + cast: wave per sorted row
    int wave = tid >> 6, lane = tid & 63;
    int srow = bx * 4 + wave;
    int orig = rowidx[srow];
    const float4v* src = (const float4v*)(x + (size_t)orig * DIN + lane * 8);
    float4v v0 = src[0], v1 = src[1];
    ushort8v o;
#pragma unroll
    for (int i = 0; i < 4; ++i) { o[i] = f2bf(v0[i]); o[4 + i] = f2bf(v1[i]); }
    *(ushort8v*)(xs + (size_t)srow * DIN + lane * 8) = o;
  } else if (bx < 3072) {
    // W1 [t][k][n] f32 -> W1T [t][n][k] bf16, 64x64 tile
    int u = bx - 2048;
    int nb = u & 7, kb = (u >> 3) & 7, t = u >> 6;
    int r = tid >> 2, c16 = (tid & 3) << 4;
    const float* src = W1 + ((size_t)t * DIN + (size_t)(kb * 64 + r)) * DH + nb * 64 + c16;
#pragma unroll
    for (int p = 0; p < 4; ++p) {
      float4v v = *(const float4v*)(src + p * 4);
#pragma unroll
      for (int i = 0; i < 4; ++i) ldsA[c16 + p * 4 + i][r] = (short)f2bf(v[i]);
    }
    __syncthreads();
    int n = tid >> 2, k16 = (tid & 3) << 4;
    short* dst = W1T + ((size_t)t * DH + nb * 64 + n) * DIN + kb * 64 + k16;
    *(ushort8v*)dst       = *(ushort8v*)&ldsA[n][k16];
    *(ushort8v*)(dst + 8) = *(ushort8v*)&ldsA[n][k16 + 8];
  } else {
    // W2 [t][k][18] -> W2T [t][32pad][512] bf16
    int u = bx - 3072;
    int t = u >> 3, k0 = (u & 7) * 64;
    for (int i = tid; i < 64 * NACT; i += 256) {
      int kk = i / NACT, j = i - kk * NACT;
      ldsB[kk * 19 + j] = W2[((size_t)t * DIN + k0 + kk) * NACT + j];
    }
    __syncthreads();
    for (int o = tid; o < 32 * 64; o += 256) {
      int j = o >> 6, kk = o & 63;
      float val = (j < NACT) ? ldsB[kk * 19 + j] : 0.0f;
      W2T[((size_t)t * 32 + j) * DIN + k0 + kk] = (short)f2bf(val);
    }
  }
}

// ============================================================ grouped GEMM1 + partial GEMM2
__global__ __launch_bounds__(256, 2) void k_gemm1(
    const short* __restrict__ xs, const float* __restrict__ bias1,
    const short* __restrict__ W1T, const short* __restrict__ W2Tg,
    const int* __restrict__ tl_task, const int* __restrict__ tl_row0,
    const int* __restrict__ tl_cnt, const int* __restrict__ slot_map,
    float* __restrict__ pbuf) {
  __shared__ __align__(16) short sA[2][BM * BK];    // 2 x 8 KB
  __shared__ __align__(16) short sB[2][GBN * BK];   // 2 x 16 KB
  __shared__ __align__(16) short sH[BM * GBN];      // 16 KB  [m][n] chunk-swizzled
  __shared__ __align__(16) short sW2[32 * GBN];     // 8 KB   [j][k] chunk-swizzled
  int s = slot_map[blockIdx.x];
  if (s < 0) return;
  int ti = s >> 2, cs = s & 3;
  int task = tl_task[ti], row0 = tl_row0[ti], mcnt = tl_cnt[ti];
  int n0 = cs * GBN;
  int tid = threadIdx.x, lane = tid & 63, wave = tid >> 6;
  int wm = wave >> 1, wn = wave & 1;

  const short* Abase = xs + (size_t)row0 * DIN;
  const short* Bbase = W1T + ((size_t)task * DH + n0) * DIN;

  // stage W2T slice once: 32 j x 128 k (chunk-swizzled)
#pragma unroll
  for (int it = 0; it < 2; ++it) {
    int ch = it * 256 + tid;
    int j = ch >> 4, c2 = ch & 15;
    ushort8v w = *(const ushort8v*)(W2Tg + ((size_t)task * 32 + j) * DIN + n0 + c2 * 8);
    *(ushort8v*)&sW2[(j * 16 + (c2 ^ (j & 7))) * 8] = w;
  }

#define STAGE(buf, k0e)                                                    \
  _Pragma("unroll") for (int it = 0; it < 2; ++it) {                       \
    int ch = it * 256 + tid; int row = ch >> 3, cc = ch & 7;               \
    int sc = cc ^ (row & 7);                                               \
    __builtin_amdgcn_global_load_lds(                                      \
        (gas_ptr)(const void*)(Abase + (size_t)row * DIN + (k0e) + sc * 8),\
        (las_ptr)(void*)(&sA[buf][ch * 8]), 16, 0, 0);                     \
  }                                                                        \
  _Pragma("unroll") for (int it = 0; it < 4; ++it) {                       \
    int ch = it * 256 + tid; int row = ch >> 3, cc = ch & 7;               \
    int sc = cc ^ (row & 7);                                               \
    __builtin_amdgcn_global_load_lds(                                      \
        (gas_ptr)(const void*)(Bbase + (size_t)row * DIN + (k0e) + sc * 8),\
        (las_ptr)(void*)(&sB[buf][ch * 8]), 16, 0, 0);                     \
  }

  STAGE(0, 0)
  asm volatile("s_waitcnt vmcnt(0)" ::: "memory");
  __syncthreads();

  float4v acc[2][4];
#pragma unroll
  for (int i = 0; i < 2; ++i)
#pragma unroll
    for (int j = 0; j < 4; ++j) acc[i][j] = (float4v)0.0f;

  for (int step = 0; step < 8; ++step) {
    int p = step & 1;
    if (step < 7) { STAGE(p ^ 1, (step + 1) * BK) }
#pragma unroll
    for (int ks = 0; ks < 2; ++ks) {
      short8v a[2], b[4];
#pragma unroll
      for (int fm = 0; fm < 2; ++fm) {
        int r = wm * 32 + fm * 16 + (lane & 15);
        int c = (ks * 4 + (lane >> 4)) ^ (r & 7);
        a[fm] = *(const short8v*)&sA[p][r * BK + c * 8];
      }
#pragma unroll
      for (int fn = 0; fn < 4; ++fn) {
        int r = wn * 64 + fn * 16 + (lane & 15);
        int c = (ks * 4 + (lane >> 4)) ^ (r & 7);
        b[fn] = *(const short8v*)&sB[p][r * BK + c * 8];
      }
#pragma unroll
      for (int fm = 0; fm < 2; ++fm)
#pragma unroll
        for (int fn = 0; fn < 4; ++fn)
          acc[fm][fn] = __builtin_amdgcn_mfma_f32_16x16x32_bf16(a[fm], b[fn], acc[fm][fn], 0, 0, 0);
    }
    asm volatile("s_waitcnt vmcnt(0)" ::: "memory");
    __syncthreads();
  }

  // epilogue-1: +bias, relu, bf16 -> sH [m][n] swizzled
  float bias[4];
#pragma unroll
  for (int fn = 0; fn < 4; ++fn)
    bias[fn] = bias1[task * DH + n0 + wn * 64 + fn * 16 + (lane & 15)];
#pragma unroll
  for (int fn = 0; fn < 4; ++fn) {
    int n = wn * 64 + fn * 16 + (lane & 15);
#pragma unroll
    for (int fm = 0; fm < 2; ++fm) {
#pragma unroll
      for (int r = 0; r < 4; ++r) {
        int m = wm * 32 + fm * 16 + ((lane >> 4) << 2) + r;
        float v = fmaxf(acc[fm][fn][r] + bias[fn], 0.0f);
        *(short*)((char*)sH + m * 256 + (((n >> 3) ^ (m & 7)) << 4) + ((n & 7) << 1)) =
            (short)f2bf(v);
      }
    }
  }
  __syncthreads();

  // partial GEMM2: this block's 128-n slice == 128-k slice of layer 2
  float4v acc2[2];
  acc2[0] = (float4v)0.0f; acc2[1] = (float4v)0.0f;
#pragma unroll
  for (int ks = 0; ks < 4; ++ks) {
    int mrow = wave * 16 + (lane & 15);
    int ca = (ks * 4 + (lane >> 4)) ^ (mrow & 7);
    short8v af = *(const short8v*)((char*)sH + mrow * 256 + (ca << 4));
#pragma unroll
    for (int fn = 0; fn < 2; ++fn) {
      int j = fn * 16 + (lane & 15);
      int cb = (ks * 4 + (lane >> 4)) ^ (j & 7);
      short8v bf = *(const short8v*)&sW2[(j * 16 + cb) * 8];
      acc2[fn] = __builtin_amdgcn_mfma_f32_16x16x32_bf16(af, bf, acc2[fn], 0, 0, 0);
    }
  }
#pragma unroll
  for (int fn = 0; fn < 2; ++fn) {
#pragma unroll
    for (int r = 0; r < 4; ++r) {
      int m = wave * 16 + ((lane >> 4) << 2) + r;
      int j = fn * 16 + (lane & 15);
      if (m < mcnt)
        pbuf[((size_t)cs * B_N + row0 + m) * 32 + j] = acc2[fn][r];
    }
  }
}

// ============================================================ reduce + softmax
__global__ __launch_bounds__(256) void k_soft(
    const float* __restrict__ pbuf, const float* __restrict__ bias2,
    const int* __restrict__ task_id, const int* __restrict__ action,
    const int* __restrict__ rowidx, float* __restrict__ out) {
  int srow = blockIdx.x * 256 + threadIdx.x;
  int orig = rowidx[srow];
  int t = task_id[orig], act = action[orig];
  float lg[NACT];
#pragma unroll
  for (int j = 0; j < NACT; ++j) {
    float v = bias2[t * NACT + j];
#pragma unroll
    for (int c = 0; c < 4; ++c) v += pbuf[((size_t)c * B_N + srow) * 32 + j];
    lg[j] = v;
  }
  float mx = lg[0];
#pragma unroll
  for (int j = 1; j < NACT; ++j) mx = fmaxf(mx, lg[j]);
  float s1 = 0.0f, s2 = 0.0f, la = 0.0f;
#pragma unroll
  for (int j = 0; j < NACT; ++j) {
    float e = __expf(lg[j] - mx);
    s1 += e; s2 += e * lg[j];
    la = (j == act) ? lg[j] : la;
  }
  float logZ = __logf(s1);
  float2v o;
  o[0] = la - mx - logZ;
  o[1] = (mx + logZ) - s2 / s1;
  *(float2v*)(out + (size_t)orig * 2) = o;
}

// ----------------------------------------------------------------------------
extern "C" void kernel_launch(void* const* d_in, const int* in_sizes, int n_in,
                              void* d_out, int out_size, void* d_ws, size_t ws_size,
                              hipStream_t stream) {
  const float* x       = (const float*)d_in[0];
  const int*   task_id = (const int*)d_in[1];
  const int*   action  = (const int*)d_in[2];
  const float* W1      = (const float*)d_in[3];
  const float* b1      = (const float*)d_in[4];
  const float* W2      = (const float*)d_in[5];
  const float* b2      = (const float*)d_in[6];
  float* out = (float*)d_out;

  char* ws = (char*)d_ws;
  int* tl_task  = (int*)ws;                    // NT_MAX
  int* tl_row0  = tl_task + NT_MAX;
  int* tl_cnt   = tl_row0 + NT_MAX;
  int* ntile    = tl_cnt + NT_MAX;
  int* slot_map = ntile + 1;                   // NSLOT ints
  int* rowidx   = (int*)(ws + 8192);           // 8192 ints -> ends 40960
  size_t off = 40960;
  short* xs   = (short*)(ws + off);  off += (size_t)(B_N + BM) * DIN * 2;    // 8.45 MB
  short* W1T  = (short*)(ws + off);  off += (size_t)NTASK * DH * DIN * 2;    // 8.39 MB
  short* W2T  = (short*)(ws + off);  off += (size_t)NTASK * 32 * DIN * 2;    // 0.52 MB
  float* pbuf = (float*)(ws + off);                                          // 4.19 MB

  k_hist<<<1, 1024, 0, stream>>>(task_id, tl_task, tl_row0, tl_cnt, ntile, slot_map, rowidx);
  k_prep<<<3200, 256, 0, stream>>>(x, W1, W2, rowidx, xs, W1T, W2T);
  k_gemm1<<<NSLOT, 256, 0, stream>>>(xs, b1, W1T, W2T, tl_task, tl_row0, tl_cnt, slot_map, pbuf);
  k_soft<<<32, 256, 0, stream>>>(pbuf, b2, task_id, action, rowidx, out);
}

// Round 5
// 48.910 us; speedup vs baseline: 1.8411x; 1.8411x over previous
//
#include <hip/hip_runtime.h>
#include <hip/hip_bf16.h>

#define B_N   8192
#define DIN   512
#define DH    512
#define NACT  18
#define NTASK 16
#define BM    64
#define GBN   128
#define BK    64
#define PJ    20      // pbuf row stride (floats)
#define NSLOT 640     // 8 residues x 80 queue slots

typedef __attribute__((ext_vector_type(8))) short  short8v;
typedef __attribute__((ext_vector_type(8))) unsigned short ushort8v;
typedef __attribute__((ext_vector_type(4))) float  float4v;
typedef __attribute__((ext_vector_type(2))) float  float2v;

typedef const __attribute__((address_space(1))) void* gas_ptr;
typedef __attribute__((address_space(3))) void* las_ptr;

__device__ __forceinline__ unsigned short f2bf(float f) {
  union { float f; unsigned int u; } c; c.f = f;
  unsigned int u = c.u;
  u += 0x7fffu + ((u >> 16) & 1u);   // RNE
  return (unsigned short)(u >> 16);
}

// ============================================================ prep kernel
// block 0          : histogram + 16-entry prefix + parallel scatter (NO serial loops)
// blocks 1..1024   : W1 [t][k][n] f32 -> W1T [t][n][k] bf16
// blocks 1025..1152: W2 [t][k][18] f32 -> W2T [t][32pad][512] bf16
__global__ __launch_bounds__(256) void k_prep(
    const float* __restrict__ W1, const float* __restrict__ W2,
    const int* __restrict__ task_id,
    short* __restrict__ W1T, short* __restrict__ W2T,
    int* __restrict__ tbl, int* __restrict__ rowidx) {
  __shared__ __align__(16) short ldsA[64][72];
  __shared__ float ldsB[64 * 19];
  __shared__ int s_cnt[NTASK], s_cur[NTASK];
  int bx = blockIdx.x, tid = threadIdx.x;

  if (bx == 0) {
    if (tid < NTASK) s_cnt[tid] = 0;
    __syncthreads();
    for (int i = tid; i < B_N; i += 256) atomicAdd(&s_cnt[task_id[i]], 1);
    __syncthreads();
    if (tid == 0) {                       // 16 iterations only
      int acc = 0;
#pragma unroll
      for (int t = 0; t < NTASK; ++t) {
        int c = s_cnt[t];
        tbl[t] = c; tbl[16 + t] = acc; s_cur[t] = acc;
        acc += c;
      }
    }
    __syncthreads();
    for (int i = tid; i < B_N; i += 256) {
      int t = task_id[i];
      rowidx[atomicAdd(&s_cur[t], 1)] = i;
    }
  } else if (bx <= 1024) {
    int u = bx - 1;
    int nb = u & 7, kb = (u >> 3) & 7, t = u >> 6;
    int r = tid >> 2, c16 = (tid & 3) << 4;
    const float* src = W1 + ((size_t)t * DIN + (size_t)(kb * 64 + r)) * DH + nb * 64 + c16;
#pragma unroll
    for (int p = 0; p < 4; ++p) {
      float4v v = *(const float4v*)(src + p * 4);
#pragma unroll
      for (int i = 0; i < 4; ++i) ldsA[c16 + p * 4 + i][r] = (short)f2bf(v[i]);
    }
    __syncthreads();
    int n = tid >> 2, k16 = (tid & 3) << 4;
    short* dst = W1T + ((size_t)t * DH + nb * 64 + n) * DIN + kb * 64 + k16;
    *(ushort8v*)dst       = *(ushort8v*)&ldsA[n][k16];
    *(ushort8v*)(dst + 8) = *(ushort8v*)&ldsA[n][k16 + 8];
  } else {
    int u = bx - 1025;
    int t = u >> 3, k0 = (u & 7) * 64;
    for (int i = tid; i < 64 * NACT; i += 256) {
      int kk = i / NACT, j = i - kk * NACT;
      ldsB[kk * 19 + j] = W2[((size_t)t * DIN + k0 + kk) * NACT + j];
    }
    __syncthreads();
    for (int o = tid; o < 32 * 64; o += 256) {
      int j = o >> 6, kk = o & 63;
      float val = (j < NACT) ? ldsB[kk * 19 + j] : 0.0f;
      W2T[((size_t)t * 32 + j) * DIN + k0 + kk] = (short)f2bf(val);
    }
  }
}

// ============================================================ grouped GEMM1 + partial GEMM2
// Per-block decode from 16-entry table; XCD affinity: physical block b<640 serves
// residue b&7 (task t -> XCD t&7), queue pos b>>3; b>=640 = spill region.
__global__ __launch_bounds__(256, 2) void k_gemm1(
    const float* __restrict__ x, const float* __restrict__ bias1,
    const short* __restrict__ W1T, const short* __restrict__ W2Tg,
    const int* __restrict__ tbl, const int* __restrict__ rowidx,
    float* __restrict__ pbuf) {
  __shared__ __align__(16) short sA[2][64 * 72];    // 2 x 9 KB (padded, reg-staged)
  __shared__ __align__(16) short sB[2][GBN * BK];   // 2 x 16 KB (gload_lds, XOR-swz)
  __shared__ __align__(16) short sH[BM * GBN];      // 16 KB
  __shared__ __align__(16) short sW2[32 * GBN];     // 8 KB
  __shared__ int s_rows[64];
  int tid = threadIdx.x, lane = tid & 63, wave = tid >> 6;

  // ---- decode (uniform, ~30 ops)
  int b = blockIdx.x;
  int t = -1, rel = 0;
  if (b < NSLOT) {
    int r = b & 7, q = b >> 3;
    int n0t = (tbl[r] + 63) >> 6, n1t = (tbl[r + 8] + 63) >> 6;
    if (q < 4 * n0t) { t = r; rel = q; }
    else if (q < 4 * (n0t + n1t)) { t = r + 8; rel = q - 4 * n0t; }
    else return;
  } else {
    int j = b - NSLOT;
    for (int r = 0; r < 8; ++r) {
      int n0t = (tbl[r] + 63) >> 6, n1t = (tbl[r + 8] + 63) >> 6;
      int P = 4 * (n0t + n1t);
      int S = (P > 80) ? (P - 80) : 0;
      if (j < S) {
        int q = 80 + j;
        if (q < 4 * n0t) { t = r; rel = q; }
        else { t = r + 8; rel = q - 4 * n0t; }
        break;
      }
      j -= S;
    }
    if (t < 0) return;
  }
  int itile = rel >> 2, cs = rel & 3;
  int cnt_t = tbl[t], off_t = tbl[16 + t];
  int row0 = off_t + itile * 64;
  int mcnt = cnt_t - itile * 64; if (mcnt > 64) mcnt = 64;
  int n0 = cs * GBN;
  int wm = wave >> 1, wn = wave & 1;

  if (tid < 64) {
    int idx = row0 + tid;
    if (idx > B_N - 1) idx = B_N - 1;
    s_rows[tid] = rowidx[idx];
  }
  // stage W2T slice once: 32 j x 128 k, chunk-swizzled
#pragma unroll
  for (int it = 0; it < 2; ++it) {
    int ch = it * 256 + tid;
    int j = ch >> 4, c2 = ch & 15;
    ushort8v w = *(const ushort8v*)(W2Tg + ((size_t)t * 32 + j) * DIN + n0 + c2 * 8);
    *(ushort8v*)&sW2[(j * 16 + (c2 ^ (j & 7))) * 8] = w;
  }
  __syncthreads();

  int arow = tid >> 2, akc = (tid & 3) << 4;       // A staging: 4 thr/row, 16 k each
  const float* xrow = x + (size_t)s_rows[arow] * DIN + akc;
  const short* Bbase = W1T + ((size_t)t * DH + n0) * DIN;

#define STAGE_B(buf, k0e)                                                    \
  _Pragma("unroll") for (int it = 0; it < 4; ++it) {                         \
    int ch = it * 256 + tid; int row = ch >> 3, cc = ch & 7;                 \
    int sc = cc ^ (row & 7);                                                 \
    __builtin_amdgcn_global_load_lds(                                        \
        (gas_ptr)(const void*)(Bbase + (size_t)row * DIN + (k0e) + sc * 8),  \
        (las_ptr)(void*)(&sB[buf][ch * 8]), 16, 0, 0);                       \
  }
#define STAGE_A(buf, k0e) {                                                  \
    const float* xs_ = xrow + (k0e);                                         \
    float4v v0 = *(const float4v*)xs_;                                       \
    float4v v1 = *(const float4v*)(xs_ + 4);                                 \
    float4v v2 = *(const float4v*)(xs_ + 8);                                 \
    float4v v3 = *(const float4v*)(xs_ + 12);                                \
    ushort8v p0, p1;                                                         \
    _Pragma("unroll") for (int i_ = 0; i_ < 4; ++i_) {                       \
      p0[i_] = f2bf(v0[i_]); p0[4 + i_] = f2bf(v1[i_]);                      \
      p1[i_] = f2bf(v2[i_]); p1[4 + i_] = f2bf(v3[i_]); }                    \
    *(ushort8v*)&sA[buf][arow * 72 + akc] = p0;                              \
    *(ushort8v*)&sA[buf][arow * 72 + akc + 8] = p1; }

  STAGE_B(0, 0)
  STAGE_A(0, 0)
  asm volatile("s_waitcnt vmcnt(0)" ::: "memory");
  __syncthreads();

  float4v acc[2][4];
#pragma unroll
  for (int i = 0; i < 2; ++i)
#pragma unroll
    for (int j = 0; j < 4; ++j) acc[i][j] = (float4v)0.0f;

  for (int step = 0; step < 8; ++step) {
    int p = step & 1;
    if (step < 7) {
      STAGE_B(p ^ 1, (step + 1) * BK)
      STAGE_A(p ^ 1, (step + 1) * BK)
    }
#pragma unroll
    for (int ks = 0; ks < 2; ++ks) {
      short8v a[2], bfr[4];
#pragma unroll
      for (int fm = 0; fm < 2; ++fm) {
        int r = wm * 32 + fm * 16 + (lane & 15);
        int c = ks * 4 + (lane >> 4);
        a[fm] = *(const short8v*)&sA[p][r * 72 + c * 8];
      }
#pragma unroll
      for (int fn = 0; fn < 4; ++fn) {
        int r = wn * 64 + fn * 16 + (lane & 15);
        int c = (ks * 4 + (lane >> 4)) ^ (r & 7);
        bfr[fn] = *(const short8v*)&sB[p][r * BK + c * 8];
      }
#pragma unroll
      for (int fm = 0; fm < 2; ++fm)
#pragma unroll
        for (int fn = 0; fn < 4; ++fn)
          acc[fm][fn] = __builtin_amdgcn_mfma_f32_16x16x32_bf16(a[fm], bfr[fn], acc[fm][fn], 0, 0, 0);
    }
    asm volatile("s_waitcnt vmcnt(0)" ::: "memory");
    __syncthreads();
  }

  // epilogue-1: +bias, relu, bf16 -> sH [m][n] chunk-swizzled
  float bias[4];
#pragma unroll
  for (int fn = 0; fn < 4; ++fn)
    bias[fn] = bias1[t * DH + n0 + wn * 64 + fn * 16 + (lane & 15)];
#pragma unroll
  for (int fn = 0; fn < 4; ++fn) {
    int n = wn * 64 + fn * 16 + (lane & 15);
#pragma unroll
    for (int fm = 0; fm < 2; ++fm) {
#pragma unroll
      for (int r = 0; r < 4; ++r) {
        int m = wm * 32 + fm * 16 + ((lane >> 4) << 2) + r;
        float v = fmaxf(acc[fm][fn][r] + bias[fn], 0.0f);
        *(short*)((char*)sH + m * 256 + (((n >> 3) ^ (m & 7)) << 4) + ((n & 7) << 1)) =
            (short)f2bf(v);
      }
    }
  }
  __syncthreads();

  // partial GEMM2: 128-n slice == 128-k slice of layer 2
  float4v acc2[2];
  acc2[0] = (float4v)0.0f; acc2[1] = (float4v)0.0f;
#pragma unroll
  for (int ks = 0; ks < 4; ++ks) {
    int mrow = wave * 16 + (lane & 15);
    int ca = (ks * 4 + (lane >> 4)) ^ (mrow & 7);
    short8v af = *(const short8v*)((char*)sH + mrow * 256 + (ca << 4));
#pragma unroll
    for (int fn = 0; fn < 2; ++fn) {
      int j = fn * 16 + (lane & 15);
      int cb = (ks * 4 + (lane >> 4)) ^ (j & 7);
      short8v bf = *(const short8v*)&sW2[(j * 16 + cb) * 8];
      acc2[fn] = __builtin_amdgcn_mfma_f32_16x16x32_bf16(af, bf, acc2[fn], 0, 0, 0);
    }
  }
#pragma unroll
  for (int fn = 0; fn < 2; ++fn) {
#pragma unroll
    for (int r = 0; r < 4; ++r) {
      int m = wave * 16 + ((lane >> 4) << 2) + r;
      int j = fn * 16 + (lane & 15);
      if (m < mcnt && j < PJ)
        pbuf[((size_t)cs * B_N + row0 + m) * PJ + j] = acc2[fn][r];
    }
  }
#undef STAGE_B
#undef STAGE_A
}

// ============================================================ reduce + softmax
__global__ __launch_bounds__(256) void k_soft(
    const float* __restrict__ pbuf, const float* __restrict__ bias2,
    const int* __restrict__ task_id, const int* __restrict__ action,
    const int* __restrict__ rowidx, float* __restrict__ out) {
  __shared__ float acc[256 * PJ];   // 20 KB
  int tid = threadIdx.x;
  int base = blockIdx.x * 256;
  // coalesced accumulate of 4 partials: 256 rows x 20 floats
#pragma unroll
  for (int it = 0; it < 5; ++it) {
    int idx = it * 256 + tid;            // 0..1279
    int row = idx / 5, j4 = idx - row * 5;
    float4v s = (float4v)0.0f;
#pragma unroll
    for (int c = 0; c < 4; ++c)
      s += *(const float4v*)&pbuf[((size_t)c * B_N + base + row) * PJ + j4 * 4];
    *(float4v*)&acc[row * PJ + j4 * 4] = s;
  }
  __syncthreads();

  int srow = base + tid;
  int orig = rowidx[srow];
  int t = task_id[orig], act = action[orig];
  float lg[NACT];
#pragma unroll
  for (int j = 0; j < NACT; ++j) lg[j] = acc[tid * PJ + j] + bias2[t * NACT + j];
  float mx = lg[0];
#pragma unroll
  for (int j = 1; j < NACT; ++j) mx = fmaxf(mx, lg[j]);
  float s1 = 0.0f, s2 = 0.0f, la = 0.0f;
#pragma unroll
  for (int j = 0; j < NACT; ++j) {
    float e = __expf(lg[j] - mx);
    s1 += e; s2 += e * lg[j];
    la = (j == act) ? lg[j] : la;
  }
  float logZ = __logf(s1);
  float2v o;
  o[0] = la - mx - logZ;
  o[1] = (mx + logZ) - s2 / s1;
  *(float2v*)(out + (size_t)orig * 2) = o;
}

// ----------------------------------------------------------------------------
extern "C" void kernel_launch(void* const* d_in, const int* in_sizes, int n_in,
                              void* d_out, int out_size, void* d_ws, size_t ws_size,
                              hipStream_t stream) {
  const float* x       = (const float*)d_in[0];
  const int*   task_id = (const int*)d_in[1];
  const int*   action  = (const int*)d_in[2];
  const float* W1      = (const float*)d_in[3];
  const float* b1      = (const float*)d_in[4];
  const float* W2      = (const float*)d_in[5];
  const float* b2      = (const float*)d_in[6];
  float* out = (float*)d_out;

  char* ws = (char*)d_ws;
  int* tbl    = (int*)ws;                  // 32 ints: [0:16) cnt, [16:32) row-offset
  int* rowidx = (int*)(ws + 4096);         // 8192 ints -> ends 36864
  size_t off = 36864;
  short* W1T  = (short*)(ws + off);  off += (size_t)NTASK * DH * DIN * 2;   // 8.39 MB
  short* W2T  = (short*)(ws + off);  off += (size_t)NTASK * 32 * DIN * 2;   // 0.52 MB
  float* pbuf = (float*)(ws + off);                                         // 2.62 MB

  k_prep<<<1153, 256, 0, stream>>>(W1, W2, task_id, W1T, W2T, tbl, rowidx);
  k_gemm1<<<NSLOT + 576, 256, 0, stream>>>(x, b1, W1T, W2T, tbl, rowidx, pbuf);
  k_soft<<<32, 256, 0, stream>>>(pbuf, b2, task_id, action, rowidx, out);
}